// Round 3
// baseline (358.296 us; speedup 1.0000x reference)
//
#include <hip/hip_runtime.h>
#include <hip/hip_bf16.h>

// FraudSNN fused kernel: GEMM (bf16 MFMA) + LIF recurrence, T=10, F=256, H=512.
// Output is FLOAT32 (reference keeps f32 throughout) — round-2 bug was writing bf16.
// Layout notes (gfx950 mfma_f32_16x16x32_bf16, verified layouts per guide §3):
//   A frag: lane holds A[row = l&15][k = (l>>4)*8 .. +8)   (8 contiguous bf16)
//   B frag: lane holds B[k ...][col = l&15] == W1[h = col][k..k+8) (W1 [H,F] row-major, K-major)
//   C/D:    lane holds D[row = (l>>4)*4 + e][col = l&15]

typedef short short8 __attribute__((ext_vector_type(8)));
typedef float f32x4 __attribute__((ext_vector_type(4)));

__device__ __forceinline__ unsigned short bfbits(float f) {
  union { __hip_bfloat16 h; unsigned short u; } c;
  c.h = __float2bfloat16(f);   // hardware RNE
  return c.u;
}

__device__ __forceinline__ unsigned int bfpack(float a, float b) {
  return (unsigned int)bfbits(a) | ((unsigned int)bfbits(b) << 16);
}

__device__ __forceinline__ float fast_sigmoid(float z) {
  float e = __expf(-z);
  return __builtin_amdgcn_rcpf(1.0f + e);
}

// 512 threads = 8 waves. Block handles 64 batch rows. Wave w owns all 64 rows x h in [w*64, w*64+64).
__global__ __launch_bounds__(512, 2)
void snn_main(const float* __restrict__ x,
              const float* __restrict__ w1,
              const float* __restrict__ b1,
              const float* __restrict__ w2,
              const float* __restrict__ b2,
              float* __restrict__ out)
{
  __shared__ __align__(16) unsigned short xt[64][264];  // bf16 bits, +8 pad
  __shared__ float red[64][9];                          // [row][wave] partial cur2

  const int tid  = threadIdx.x;
  const int lane = tid & 63;
  const int wave = tid >> 6;
  const int l15  = lane & 15;
  const int lq   = lane >> 4;
  const long b0  = (long)blockIdx.x * 64;
  const int h0   = wave * 64;

  float w2l[4], b1l[4];
#pragma unroll
  for (int ct = 0; ct < 4; ++ct) {
    int h = h0 + ct * 16 + l15;
    w2l[ct] = w2[h];
    b1l[ct] = b1[h];
  }
  const float bias2 = b2[0];

  float mem1[4][4][4];
#pragma unroll
  for (int rt = 0; rt < 4; ++rt)
#pragma unroll
    for (int ct = 0; ct < 4; ++ct)
#pragma unroll
      for (int e = 0; e < 4; ++e) mem1[rt][ct][e] = 0.f;

  float mem2 = 0.f, spksum = 0.f;   // meaningful on tid<64 only

  for (int t = 0; t < 10; ++t) {
    // ---- stage x[b0..b0+63, t, :] -> LDS bf16 ----
#pragma unroll
    for (int j = 0; j < 8; ++j) {
      int i  = tid + j * 512;
      int r  = i >> 6;
      int c4 = i & 63;
      const float4 v = *reinterpret_cast<const float4*>(x + ((b0 + r) * 10 + t) * 256 + c4 * 4);
      *reinterpret_cast<uint2*>(&xt[r][c4 * 4]) =
          make_uint2(bfpack(v.x, v.y), bfpack(v.z, v.w));
    }
    __syncthreads();

    // ---- GEMM: cur1 = x @ W1^T + b1 (acc init = b1) ----
    f32x4 acc[4][4];
#pragma unroll
    for (int rt = 0; rt < 4; ++rt)
#pragma unroll
      for (int ct = 0; ct < 4; ++ct) {
        f32x4 c = { b1l[ct], b1l[ct], b1l[ct], b1l[ct] };
        acc[rt][ct] = c;
      }

#pragma unroll
    for (int kk = 0; kk < 8; ++kk) {
      short8 a[4], bfr[4];
#pragma unroll
      for (int rt = 0; rt < 4; ++rt)
        a[rt] = *reinterpret_cast<const short8*>(&xt[rt * 16 + l15][kk * 32 + lq * 8]);
#pragma unroll
      for (int ct = 0; ct < 4; ++ct) {
        // W1 fp32 direct from global (L2-resident), convert to bf16 in-register
        const float* wp = w1 + (h0 + ct * 16 + l15) * 256 + kk * 32 + lq * 8;
        const float4 v0 = *reinterpret_cast<const float4*>(wp);
        const float4 v1 = *reinterpret_cast<const float4*>(wp + 4);
        union { unsigned int u[4]; short8 s; } cv;
        cv.u[0] = bfpack(v0.x, v0.y);
        cv.u[1] = bfpack(v0.z, v0.w);
        cv.u[2] = bfpack(v1.x, v1.y);
        cv.u[3] = bfpack(v1.z, v1.w);
        bfr[ct] = cv.s;
      }
#pragma unroll
      for (int rt = 0; rt < 4; ++rt)
#pragma unroll
        for (int ct = 0; ct < 4; ++ct)
          acc[rt][ct] = __builtin_amdgcn_mfma_f32_16x16x32_bf16(a[rt], bfr[ct], acc[rt][ct], 0, 0, 0);
    }

    // ---- LIF1 + partial W2 dot ----
    float pr[4][4];
#pragma unroll
    for (int rt = 0; rt < 4; ++rt)
#pragma unroll
      for (int e = 0; e < 4; ++e) pr[rt][e] = 0.f;

#pragma unroll
    for (int rt = 0; rt < 4; ++rt)
#pragma unroll
      for (int ct = 0; ct < 4; ++ct)
#pragma unroll
        for (int e = 0; e < 4; ++e) {
          float m   = fmaf(mem1[rt][ct][e], 0.9f, acc[rt][ct][e]);  // beta*mem + cur1
          float spk = fast_sigmoid(fmaf(m, 10.f, -10.f));           // sigmoid(10*(m-1))
          mem1[rt][ct][e] = m - spk;
          pr[rt][e] = fmaf(spk, w2l[ct], pr[rt][e]);
        }

    // reduce across the 16 lanes (h axis) sharing each row
#pragma unroll
    for (int rt = 0; rt < 4; ++rt)
#pragma unroll
      for (int e = 0; e < 4; ++e) {
        float v = pr[rt][e];
        v += __shfl_xor(v, 1);
        v += __shfl_xor(v, 2);
        v += __shfl_xor(v, 4);
        v += __shfl_xor(v, 8);
        pr[rt][e] = v;
      }
    if (l15 == 0) {
#pragma unroll
      for (int rt = 0; rt < 4; ++rt)
#pragma unroll
        for (int e = 0; e < 4; ++e)
          red[rt * 16 + lq * 4 + e][wave] = pr[rt][e];
    }
    __syncthreads();

    // ---- LIF2 on wave 0: one thread per batch row ----
    if (tid < 64) {
      float c2 = bias2;
#pragma unroll
      for (int w = 0; w < 8; ++w) c2 += red[tid][w];
      float m   = fmaf(mem2, 0.9f, c2);
      float spk = fast_sigmoid(fmaf(m, 10.f, -10.f));
      mem2   = m - spk;
      spksum += spk;
    }
    __syncthreads();
  }

  if (tid < 64) {
    float y = fast_sigmoid(spksum * 0.1f);
    out[b0 + tid] = y;                      // FLOAT32 output
  }
}

extern "C" void kernel_launch(void* const* d_in, const int* in_sizes, int n_in,
                              void* d_out, int out_size, void* d_ws, size_t ws_size,
                              hipStream_t stream) {
  const float* x  = (const float*)d_in[0];
  const float* W1 = (const float*)d_in[1];
  const float* b1 = (const float*)d_in[2];
  const float* W2 = (const float*)d_in[3];
  const float* b2 = (const float*)d_in[4];
  float* out = (float*)d_out;
  (void)d_ws; (void)ws_size; (void)in_sizes; (void)n_in;

  // out_size == B == 32768; each block handles 64 batch rows
  snn_main<<<out_size / 64, 512, 0, stream>>>(x, W1, b1, W2, b2, out);
}